// Round 12
// baseline (3473.309 us; speedup 1.0000x reference)
//
#include <hip/hip_runtime.h>

// GRNN (NRI) encoder, MI355X gfx950.
// B=8, N=16, T=64, D=4, H=256, E=240, BT=512, BR=1920.
// MLPs: fp16 MFMA gather-GEMMs, BN fused into consumer staging.
// LSTM: x@Wih^T precomputed per 16-step chunk (gate-interleaved layout);
// recurrent part = 240 co-resident blocks (60 rgrps x 4 colq, same-XCD
// siblings), Whh slice (128 KB) persistent in LDS, h-quadrant exchange via
// agent-scope parity mailboxes. Step skeleton: LBAR (lgkm-only) for LDS-only
// hazards, one vmcnt-draining syncthreads (publish->flag), raw s_barrier
// after spin; hout/state writes + xw prefetch overlapped with the spin;
// step 15 skips the exchange entirely.

typedef __attribute__((ext_vector_type(4))) float f32x4;
typedef __attribute__((ext_vector_type(8))) _Float16 f16x8;
typedef unsigned long long u64;

#define DEVFN static __device__ __forceinline__

DEVFN float elu_f(float x)  { return x > 0.f ? x : __expf(x) - 1.f; }
DEVFN float sig_f(float x)  { return 1.f / (1.f + __expf(-x)); }
DEVFN float tanh_f(float x) { return 1.f - 2.f / (1.f + __expf(2.f * x)); }

// lgkmcnt-only barrier: orders LDS without draining vmem.
#define LBAR() asm volatile("s_waitcnt lgkmcnt(0)\n\ts_barrier" ::: "memory")
#define RBAR() asm volatile("s_barrier" ::: "memory")

#define M_ID  0
#define M_N2E 1
#define M_M4  2
#define M_L0C 3   // xw0 chunk: q=(r*16+tt): A0[(b*64+tc+tt)*240+e], BN st0
#define M_IDC 4   // xw1/2 chunk: A0[(q>>4)*64 + tc + (q&15)]

// ---------------------------------------------------------------------------
// Gather-GEMM: out[M,O] = epi(gatherA[M,K] @ W[O,K]^T + bias).
// ---------------------------------------------------------------------------
template<int MODE, bool DOELU>
__global__ __launch_bounds__(256) void gemmg(
    const _Float16* __restrict__ A0, const _Float16* __restrict__ A1,
    const float* __restrict__ st0, const float* __restrict__ st1,
    const int* __restrict__ sidx, const int* __restrict__ ridx,
    const _Float16* __restrict__ W, const float* __restrict__ bias,
    _Float16* __restrict__ out, int M, int O, int tc)
{
    constexpr int NSEG = (MODE == M_M4) ? 3 : ((MODE == M_N2E) ? 2 : 1);
    constexpr bool HAS_ST = (MODE == M_N2E) || (MODE == M_M4) || (MODE == M_L0C);
    const int K = NSEG * 256;

    __shared__ _Float16 As[128][40];
    __shared__ _Float16 Ws[128][40];

    const int tid  = threadIdx.x;
    const int lane = tid & 63;
    const int wv   = tid >> 6;
    const int wr   = wv >> 1, wc = wv & 1;
    const int lr   = lane & 15, kg = lane >> 4;
    const int m0   = blockIdx.x * 128;
    const int o0   = blockIdx.y * 128;
    const int srow = tid >> 1;
    const int scol = (tid & 1) * 16;

    const _Float16* ab[3] = {nullptr, nullptr, nullptr};
    const float*   stp[3] = {nullptr, nullptr, nullptr};
    {
        int r = m0 + srow;
        if constexpr (MODE == M_ID) {
            ab[0] = A0 + (size_t)r * 256;
        } else if constexpr (MODE == M_N2E) {
            int bt = r / 240, e = r - bt * 240;
            ab[0] = A0 + (size_t)(bt * 16 + sidx[e]) * 256;
            ab[1] = A0 + (size_t)(bt * 16 + ridx[e]) * 256;
            stp[0] = st0; stp[1] = st0;
        } else if constexpr (MODE == M_M4) {
            int bt = r / 240, e = r - bt * 240;
            ab[0] = A0 + (size_t)(bt * 16 + sidx[e]) * 256;
            ab[1] = A0 + (size_t)(bt * 16 + ridx[e]) * 256;
            ab[2] = A1 + (size_t)r * 256;
            stp[0] = st0; stp[1] = st0; stp[2] = st1;
        } else if constexpr (MODE == M_L0C) {
            int rr = r >> 4, tt = r & 15;
            int b = rr / 240, e = rr - b * 240;
            ab[0] = A0 + (size_t)((b * 64 + tc + tt) * 240 + e) * 256;
            stp[0] = st0;
        } else {  // M_IDC
            ab[0] = A0 + (size_t)((r >> 4) * 64 + tc + (r & 15)) * 256;
        }
    }
    const _Float16* wrow = W + (size_t)(o0 + srow) * K;

    f32x4 acc[4][4];
#pragma unroll
    for (int i = 0; i < 4; ++i)
#pragma unroll
        for (int j = 0; j < 4; ++j) acc[i][j] = (f32x4)0.f;

#pragma unroll
    for (int seg = 0; seg < NSEG; ++seg) {
        const _Float16* asrc = ab[seg];
        const float*    st   = stp[seg];
#pragma unroll 1
        for (int kk = 0; kk < 256; kk += 32) {
            f16x8 v0 = *(const f16x8*)(asrc + kk + scol);
            f16x8 v1 = *(const f16x8*)(asrc + kk + scol + 8);
            if constexpr (HAS_ST) {
#pragma unroll
                for (int j = 0; j < 8; ++j) {
                    int c0 = kk + scol + j, c1 = c0 + 8;
                    v0[j] = (_Float16)((float)v0[j] * st[512 + c0] + st[768 + c0]);
                    v1[j] = (_Float16)((float)v1[j] * st[512 + c1] + st[768 + c1]);
                }
            }
            f16x8 w0 = *(const f16x8*)(wrow + seg * 256 + kk + scol);
            f16x8 w1 = *(const f16x8*)(wrow + seg * 256 + kk + scol + 8);
            *(f16x8*)&As[srow][scol]     = v0;
            *(f16x8*)&As[srow][scol + 8] = v1;
            *(f16x8*)&Ws[srow][scol]     = w0;
            *(f16x8*)&Ws[srow][scol + 8] = w1;
            __syncthreads();

            f16x8 af[4], bf[4];
#pragma unroll
            for (int rf = 0; rf < 4; ++rf)
                af[rf] = *(const f16x8*)&As[wr * 64 + rf * 16 + lr][kg * 8];
#pragma unroll
            for (int cf = 0; cf < 4; ++cf)
                bf[cf] = *(const f16x8*)&Ws[wc * 64 + cf * 16 + lr][kg * 8];
#pragma unroll
            for (int rf = 0; rf < 4; ++rf)
#pragma unroll
                for (int cf = 0; cf < 4; ++cf)
                    acc[rf][cf] = __builtin_amdgcn_mfma_f32_16x16x32_f16(
                        af[rf], bf[cf], acc[rf][cf], 0, 0, 0);
            __syncthreads();
        }
    }

#pragma unroll
    for (int rf = 0; rf < 4; ++rf) {
#pragma unroll
        for (int cf = 0; cf < 4; ++cf) {
            int c = o0 + wc * 64 + cf * 16 + lr;
            float bv = bias ? bias[c] : 0.f;
#pragma unroll
            for (int rg = 0; rg < 4; ++rg) {
                int r = m0 + wr * 64 + rf * 16 + kg * 4 + rg;
                float v = acc[rf][cf][rg] + bv;
                if (DOELU) v = elu_f(v);
                out[(size_t)r * O + c] = (_Float16)v;
            }
        }
    }
}

// ---------------------------------------------------------------------------
__global__ void mlp1_g1(const float* __restrict__ inp, const float* __restrict__ w1,
                        const float* __restrict__ b1, _Float16* __restrict__ out)
{
    int idx = blockIdx.x * 256 + threadIdx.x;
    int o = idx & 255, row = idx >> 8;
    int bt = row >> 4, n = row & 15, b = bt >> 6, t = bt & 63;
    const float* xp = inp + (((b * 16 + n) * 64 + t) << 2);
    const float* wp = w1 + (o << 2);
    float v = b1[o] + xp[0] * wp[0] + xp[1] * wp[1] + xp[2] * wp[2] + xp[3] * wp[3];
    out[idx] = (_Float16)elu_f(v);
}

__global__ void decode_k(const float* __restrict__ rel_rec, const float* __restrict__ rel_send,
                         int* __restrict__ sidx, int* __restrict__ ridx,
                         int* __restrict__ nodeEdges)
{
    int tid = threadIdx.x;
    if (tid < 240) {
        float as = 0.f, ar = 0.f;
        for (int n = 0; n < 16; ++n) {
            as += rel_send[tid * 16 + n] * (float)n;
            ar += rel_rec[tid * 16 + n] * (float)n;
        }
        sidx[tid] = (int)(as + 0.5f);
        ridx[tid] = (int)(ar + 0.5f);
    }
    __syncthreads();
    if (tid < 16) {
        int k = 0;
        for (int e = 0; e < 240; ++e)
            if (ridx[e] == tid) nodeEdges[tid * 15 + (k++)] = e;
    }
}

__global__ void cvt16(const float* __restrict__ src, _Float16* __restrict__ dst, int n)
{
    int i = blockIdx.x * 256 + threadIdx.x;
    if (i < n) dst[i] = (_Float16)src[i];
}

// Wih rows permuted so GEMM output col c' = [hcol=c'>>2][gate=c'&3]
__global__ void cvtperm(const float* __restrict__ src, _Float16* __restrict__ dst)
{
    int idx = blockIdx.x * 256 + threadIdx.x;   // 786432 total
    int k = idx & 255;
    int cp = (idx >> 8) & 1023;
    int l = idx >> 18;
    dst[idx] = (_Float16)src[((size_t)l * 1024 + (cp & 3) * 256 + (cp >> 2)) * 256 + k];
}

// ---------------------------------------------------------------------------
// Whh fragment pack: W2[l][cq][w4][g][kc][lane][8] f16
// ---------------------------------------------------------------------------
__global__ void wprep2(const float* __restrict__ whh, _Float16* __restrict__ W2)
{
    int idx = blockIdx.x * 256 + threadIdx.x;   // 98304 total
    int lane = idx & 63; int u = idx >> 6;
    int kc = u & 7; u >>= 3;
    int g  = u & 3; u >>= 2;
    int w  = u & 3; u >>= 2;
    int cq = u & 3; u >>= 2;
    int l  = u;
    int gatecol = g * 256 + cq * 64 + w * 16 + (lane & 15);
    int k = kc * 32 + (lane >> 4) * 8;
    const float* src = whh + (size_t)l * 262144 + (size_t)gatecol * 256 + k;
    f16x8 v;
#pragma unroll
    for (int j = 0; j < 8; ++j) v[j] = (_Float16)src[j];
    *(f16x8*)&W2[(size_t)idx * 8] = v;
}

// ---------------------------------------------------------------------------
__global__ void bn_stats(const _Float16* __restrict__ h, float* __restrict__ stats,
                         int Mrows, int rowsPerBlk)
{
    int col = threadIdx.x;
    int r0 = blockIdx.x * rowsPerBlk;
    int r1 = r0 + rowsPerBlk; if (r1 > Mrows) r1 = Mrows;
    float s = 0.f, q = 0.f;
    for (int r = r0; r < r1; ++r) {
        float v = (float)h[(size_t)r * 256 + col];
        s += v; q += v * v;
    }
    atomicAdd(&stats[col], s);
    atomicAdd(&stats[256 + col], q);
}

__global__ void bn_fin(float* __restrict__ stats, const float* __restrict__ g,
                       const float* __restrict__ be, float invM)
{
    int c = threadIdx.x;
    float m  = stats[c] * invM;
    float vr = stats[256 + c] * invM - m * m;
    float sc = rsqrtf(vr + 1e-5f) * g[c];
    stats[512 + c] = sc;
    stats[768 + c] = be[c] - m * sc;
}

__global__ void e2n_k(const _Float16* __restrict__ x2, const float* __restrict__ st,
                      const int* __restrict__ nodeEdges, _Float16* __restrict__ out)
{
    int idx = blockIdx.x * 256 + threadIdx.x;
    int c = (idx & 31) * 8;
    int n = (idx >> 5) & 15;
    int bt = idx >> 9;
    float s[8] = {0, 0, 0, 0, 0, 0, 0, 0};
    for (int k = 0; k < 15; ++k) {
        int e = nodeEdges[n * 15 + k];
        f16x8 v = *(const f16x8*)&x2[(size_t)(bt * 240 + e) * 256 + c];
#pragma unroll
        for (int j = 0; j < 8; ++j) s[j] += (float)v[j];
    }
    f16x8 r;
#pragma unroll
    for (int j = 0; j < 8; ++j)
        r[j] = (_Float16)((st[512 + c + j] * s[j] + 15.f * st[768 + c + j]) * 0.0625f);
    *(f16x8*)&out[(size_t)(bt * 16 + n) * 256 + c] = r;
}

// ---------------------------------------------------------------------------
// Recurrent chunk kernel. Grid 256 (16 idle): colq = blockIdx>>6,
// rgrp = blockIdx&63 (same-XCD siblings). 256 threads (4 waves).
// Step: MFMA | LBAR | pointwise+publish | syncthreads | flag; hout/state/
// prefetch overlapped with spin | s_barrier | pull+scatter | LBAR.
// Step 15: no exchange (own-quadrant state only).
// ---------------------------------------------------------------------------
#define STEP(TT, XPU, XPN) do {                                                \
    const int t_ = tc + (TT);                                                  \
    f32x4 acc[4][2];                                                           \
    _Pragma("unroll")                                                          \
    for (int g = 0; g < 4; ++g)                                                \
        _Pragma("unroll")                                                      \
        for (int rt = 0; rt < 2; ++rt) acc[g][rt] = (f32x4)0.f;                \
    _Pragma("unroll")                                                          \
    for (int kc = 0; kc < 8; ++kc) {                                           \
        const int kb = kc * 64 + kg * 16;                                      \
        const int o0_ = (lr * 512 + kb) ^ ((lr & 7) << 4);                     \
        const int o1_ = ((16 + lr) * 512 + kb) ^ (((16 + lr) & 7) << 4);       \
        f16x8 a0 = *(const f16x8*)(hfulb + o0_);                               \
        f16x8 a1 = *(const f16x8*)(hfulb + o1_);                               \
        _Pragma("unroll")                                                      \
        for (int g = 0; g < 4; ++g) {                                          \
            f16x8 bf = *(const f16x8*)&Wlds[(((w * 4 + g) * 8 + kc) * 64 + lane) * 8]; \
            acc[g][0] = __builtin_amdgcn_mfma_f32_16x16x32_f16(a0, bf, acc[g][0], 0, 0, 0); \
            acc[g][1] = __builtin_amdgcn_mfma_f32_16x16x32_f16(a1, bf, acc[g][1], 0, 0, 0); \
        }                                                                      \
    }                                                                          \
    LBAR();   /* all waves done reading hfulb */                               \
    _Float16 hv0[4], hv1[4];                                                   \
    _Pragma("unroll")                                                          \
    for (int rt = 0; rt < 2; ++rt)                                             \
        _Pragma("unroll")                                                      \
        for (int rg = 0; rg < 4; ++rg) {                                       \
            int row = rt * 16 + kg * 4 + rg;                                   \
            union { u64 u; _Float16 h[4]; } xu; xu.u = XPU[rt * 4 + rg];       \
            float gi = acc[0][rt][rg] + (float)xu.h[0] + bs[0];                \
            float gf = acc[1][rt][rg] + (float)xu.h[1] + bs[1];                \
            float gg = acc[2][rt][rg] + (float)xu.h[2] + bs[2];                \
            float go = acc[3][rt][rg] + (float)xu.h[3] + bs[3];                \
            float c  = sig_f(gf) * cst[rt][rg] + sig_f(gi) * tanh_f(gg);       \
            cst[rt][rg] = c;                                                   \
            float h = sig_f(go) * tanh_f(c);                                   \
            _Float16 h16 = (_Float16)h;                                        \
            if (rt == 0) hv0[rg] = h16; else hv1[rg] = h16;                    \
            int off = (row * 512 + col * 2) ^ ((row & 7) << 4);                \
            *(_Float16*)(hfulb + off) = h16;                                   \
        }                                                                      \
    if ((TT) < 15) {                                                           \
        const int lc = w * 16 + lr;                                            \
        union { _Float16 h[4]; u64 u; } pk;                                    \
        pk.h[0] = hv0[0]; pk.h[1] = hv0[1]; pk.h[2] = hv0[2]; pk.h[3] = hv0[3];\
        u64 p0 = pk.u;                                                         \
        pk.h[0] = hv1[0]; pk.h[1] = hv1[1]; pk.h[2] = hv1[2]; pk.h[3] = hv1[3];\
        u64 p1 = pk.u;                                                         \
        u64* hb = hex + ((size_t)fid * 2 + (t_ & 1)) * 512;                    \
        __hip_atomic_store(&hb[(lc * 2 + 0) * 4 + kg], p0,                     \
                           __ATOMIC_RELAXED, __HIP_MEMORY_SCOPE_AGENT);        \
        __hip_atomic_store(&hb[(lc * 2 + 1) * 4 + kg], p1,                     \
                           __ATOMIC_RELAXED, __HIP_MEMORY_SCOPE_AGENT);        \
    }                                                                          \
    __syncthreads();   /* publishes drained; own-col hfulb writes visible */   \
    if ((TT) < 15 && tid == 0)                                                 \
        __hip_atomic_store(&flags[fid], t_ + 1,                                \
                           __ATOMIC_RELEASE, __HIP_MEMORY_SCOPE_AGENT);        \
    {   /* overlapped with spin: hout/hfinal/hstate + xw prefetch */           \
        int row = tid >> 3, cg = colq * 64 + (tid & 7) * 8;                    \
        int off = (row * 512 + cg * 2) ^ ((row & 7) << 4);                     \
        f16x8 v = *(const f16x8*)(hfulb + off);                                \
        if (hout)                                                              \
            *(f16x8*)&hout[((size_t)(r0 + row) * 64 + t_) * 256 + cg] = v;     \
        if (hfinal && t_ == 63)                                                \
            *(f16x8*)&hfinal[(size_t)(r0 + row) * 256 + cg] = v;               \
        if ((TT) == 15) {                                                      \
            *(f16x8*)&hstate[(size_t)(r0 + row) * 256 + cg] = v;               \
            _Pragma("unroll")                                                  \
            for (int rt = 0; rt < 2; ++rt)                                     \
                _Pragma("unroll")                                              \
                for (int rg = 0; rg < 4; ++rg)                                 \
                    cstate[(size_t)(r0 + rt * 16 + kg * 4 + rg) * 256 + col] = cst[rt][rg]; \
        }                                                                      \
    }                                                                          \
    if ((TT) < 15) {                                                           \
        const int ttn_ = (TT) + 1;                                             \
        _Pragma("unroll")                                                      \
        for (int rt = 0; rt < 2; ++rt)                                         \
            _Pragma("unroll")                                                  \
            for (int rg = 0; rg < 4; ++rg) {                                   \
                int row = rt * 16 + kg * 4 + rg;                               \
                XPN[rt * 4 + rg] = *(const u64*)(xwb                           \
                    + ((size_t)(r0 + row) * 16 + ttn_) * 1024);                \
            }                                                                  \
        if (tid < 3) {                                                         \
            int sq_ = tid + (tid >= colq ? 1 : 0);                             \
            while (__hip_atomic_load(&flags[rgrp * 4 + sq_],                   \
                     __ATOMIC_ACQUIRE, __HIP_MEMORY_SCOPE_AGENT) < t_ + 1) {}  \
        }                                                                      \
        RBAR();                                                                \
        u64 pv_[6];                                                            \
        _Pragma("unroll")                                                      \
        for (int j_ = 0; j_ < 6; ++j_) {                                       \
            int sbi_ = j_ >> 1;                                                \
            int sq_  = sbi_ + (sbi_ >= colq ? 1 : 0);                          \
            int idx_ = tid + (j_ & 1) * 256;                                   \
            pv_[j_] = __hip_atomic_load(                                       \
                &hex[(((size_t)rgrp * 4 + sq_) * 2 + (t_ & 1)) * 512 + idx_],  \
                __ATOMIC_RELAXED, __HIP_MEMORY_SCOPE_AGENT);                   \
        }                                                                      \
        _Pragma("unroll")                                                      \
        for (int j_ = 0; j_ < 6; ++j_) {                                       \
            int sbi_ = j_ >> 1;                                                \
            int sq_  = sbi_ + (sbi_ >= colq ? 1 : 0);                          \
            int idx_ = tid + (j_ & 1) * 256;                                   \
            int lc_ = idx_ >> 3, rt_ = (idx_ >> 2) & 1, kg_ = idx_ & 3;        \
            int cg_ = sq_ * 64 + lc_;                                          \
            union { u64 u; _Float16 h[4]; } un_; un_.u = pv_[j_];              \
            _Pragma("unroll")                                                  \
            for (int rg_ = 0; rg_ < 4; ++rg_) {                                \
                int row_ = rt_ * 16 + kg_ * 4 + rg_;                           \
                int off_ = (row_ * 512 + cg_ * 2) ^ ((row_ & 7) << 4);         \
                *(_Float16*)(hfulb + off_) = un_.h[rg_];                       \
            }                                                                  \
        }                                                                      \
        LBAR();   /* scatter visible before next MFMA */                       \
    }                                                                          \
} while (0)

__global__ __launch_bounds__(256) void rec_k(
    const _Float16* __restrict__ xw,     // [30720,1024] gate-interleaved
    const _Float16* __restrict__ W2l,    // [cq][w4][g][kc][64][8]
    const float* __restrict__ bih, const float* __restrict__ bhh,   // [1024]
    _Float16* __restrict__ hout,         // [122880,256] or null
    _Float16* __restrict__ hfinal,       // [1920,256] or null
    u64* __restrict__ hex,               // [240][2][512]
    int* __restrict__ flags,             // [240] zeroed per chunk
    int tc,
    _Float16* __restrict__ hstate,       // [1920,256]
    float* __restrict__ cstate)          // [1920,256]
{
    __shared__ _Float16 Wlds[65536];     // 128 KB
    __shared__ char hfulb[16384];        // [32][256] f16, XOR-swizzled

    const int colq = blockIdx.x >> 6;
    const int rgrp = blockIdx.x & 63;
    if (rgrp >= 60) return;

    const int tid  = threadIdx.x;
    const int lane = tid & 63;
    const int w    = tid >> 6;
    const int lr   = lane & 15, kg = lane >> 4;
    const int fid  = rgrp * 4 + colq;
    const int r0   = rgrp * 32;
    const int col  = colq * 64 + w * 16 + lr;

    {
        const f16x8* src = (const f16x8*)(W2l + (size_t)colq * 65536);
        f16x8* dst = (f16x8*)Wlds;
        for (int i = tid; i < 8192; i += 256) dst[i] = src[i];
    }

    float cst[2][4];
    if (tc == 0) {
        for (int i = tid; i < 2048; i += 256) ((u64*)hfulb)[i] = 0ULL;
#pragma unroll
        for (int rt = 0; rt < 2; ++rt)
#pragma unroll
            for (int rg = 0; rg < 4; ++rg) cst[rt][rg] = 0.f;
    } else {
        for (int i = tid; i < 1024; i += 256) {
            int row = i >> 5, c8 = (i & 31) * 8;
            f16x8 v = *(const f16x8*)&hstate[(size_t)(r0 + row) * 256 + c8];
            int off = (row * 512 + c8 * 2) ^ ((row & 7) << 4);
            *(f16x8*)(hfulb + off) = v;
        }
#pragma unroll
        for (int rt = 0; rt < 2; ++rt)
#pragma unroll
            for (int rg = 0; rg < 4; ++rg)
                cst[rt][rg] = cstate[(size_t)(r0 + rt * 16 + kg * 4 + rg) * 256 + col];
    }

    float bs[4];
#pragma unroll
    for (int g = 0; g < 4; ++g) bs[g] = bih[g * 256 + col] + bhh[g * 256 + col];

    const _Float16* xwb = xw + (size_t)col * 4;

    u64 xpA[8], xpB[8];
#pragma unroll
    for (int rt = 0; rt < 2; ++rt)
#pragma unroll
        for (int rg = 0; rg < 4; ++rg) {
            int row = rt * 16 + kg * 4 + rg;
            xpA[rt * 4 + rg] = *(const u64*)(xwb + (size_t)(r0 + row) * 16 * 1024);
        }
    __syncthreads();

#pragma unroll 1
    for (int it = 0; it < 8; ++it) {
        STEP(it * 2,     xpA, xpB);
        STEP(it * 2 + 1, xpB, xpA);
    }
}

// Final FC: out[r, 0:2] = hfinal[r] @ fco_w^T + fco_b
__global__ void fco_k(const _Float16* __restrict__ hout, const float* __restrict__ w,
                      const float* __restrict__ b, float* __restrict__ out)
{
    int row = blockIdx.x;
    int lane = threadIdx.x;   // 64
    const _Float16* hp = hout + (size_t)row * 256;
    float s0 = 0.f, s1 = 0.f;
    for (int k = lane; k < 256; k += 64) {
        float v = (float)hp[k];
        s0 += v * w[k];
        s1 += v * w[256 + k];
    }
#pragma unroll
    for (int off = 32; off; off >>= 1) {
        s0 += __shfl_down(s0, off, 64);
        s1 += __shfl_down(s1, off, 64);
    }
    if (lane == 0) {
        out[row * 2 + 0] = s0 + b[0];
        out[row * 2 + 1] = s1 + b[1];
    }
}

// ---------------------------------------------------------------------------
extern "C" void kernel_launch(void* const* d_in, const int* in_sizes, int n_in,
                              void* d_out, int out_size, void* d_ws, size_t ws_size,
                              hipStream_t stream)
{
    const float* inputs   = (const float*)d_in[0];
    const float* rel_rec  = (const float*)d_in[1];
    const float* rel_send = (const float*)d_in[2];
    const float *mw1[4], *mb1[4], *mw2[4], *mb2[4], *mg[4], *mbe[4];
    for (int i = 0; i < 4; ++i) {
        mw1[i] = (const float*)d_in[3 + 6 * i + 0];
        mb1[i] = (const float*)d_in[3 + 6 * i + 1];
        mw2[i] = (const float*)d_in[3 + 6 * i + 2];
        mb2[i] = (const float*)d_in[3 + 6 * i + 3];
        mg [i] = (const float*)d_in[3 + 6 * i + 4];
        mbe[i] = (const float*)d_in[3 + 6 * i + 5];
    }
    const float* lstm_wih = (const float*)d_in[27];
    const float* lstm_whh = (const float*)d_in[28];
    const float* lstm_bih = (const float*)d_in[29];
    const float* lstm_bhh = (const float*)d_in[30];
    const float* fco_w    = (const float*)d_in[31];
    const float* fco_b    = (const float*)d_in[32];
    float* out = (float*)d_out;
    (void)in_sizes; (void)n_in; (void)out_size; (void)ws_size;

    char* ws = (char*)d_ws;
    size_t off = 0;
    auto alloc = [&](size_t bytes) -> void* {
        void* p = ws + off;
        off = (off + bytes + 255) & ~(size_t)255;
        return p;
    };

    float* stats    = (float*)alloc(4 * 1024 * 4);
    int*   sidx     = (int*)alloc(240 * 4);
    int*   ridx     = (int*)alloc(240 * 4);
    int*   nodeEdges= (int*)alloc(240 * 4);
    int*   flags    = (int*)alloc(12 * 240 * 4);
    u64*   hexbuf   = (u64*)alloc((size_t)240 * 2 * 512 * 8);

    const int wsz[7] = {65536, 131072, 65536, 65536, 65536, 196608, 65536};
    const float* wsrc[7] = {mw2[0], mw1[1], mw2[1], mw1[2], mw2[2], mw1[3], mw2[3]};
    _Float16* w16[7];
    for (int i = 0; i < 7; ++i) w16[i] = (_Float16*)alloc((size_t)wsz[i] * 2);
    _Float16* wihp = (_Float16*)alloc((size_t)786432 * 2);    // gate-permuted Wih
    _Float16* W2   = (_Float16*)alloc((size_t)786432 * 2);    // packed Whh frags

    const size_t SM = (size_t)8192 * 256;
    _Float16* h1    = (_Float16*)alloc(SM * 2);
    _Float16* h1b   = (_Float16*)alloc(SM * 2);
    _Float16* xn    = (_Float16*)alloc(SM * 2);
    _Float16* x3h   = (_Float16*)alloc(SM * 2);
    _Float16* x3raw = (_Float16*)alloc(SM * 2);
    _Float16* hfinal= (_Float16*)alloc((size_t)1920 * 256 * 2);
    _Float16* hstate= (_Float16*)alloc((size_t)1920 * 256 * 2);
    float*    cstate= (float*)alloc((size_t)1920 * 256 * 4);

    const size_t BIG = (size_t)122880 * 256;
    _Float16* P  = (_Float16*)alloc(BIG * 2);                 // also hout
    _Float16* Q  = (_Float16*)alloc(BIG * 2);
    _Float16* XW = (_Float16*)alloc((size_t)30720 * 1024 * 2);

    float* st1 = stats, *st2 = stats + 1024, *st3 = stats + 2048, *st4 = stats + 3072;

    auto bn = [&](const _Float16* h, int Mrows, float* st, const float* g, const float* be) {
        hipMemsetAsync(st, 0, 512 * sizeof(float), stream);
        int nblk = (Mrows > 20000) ? 240 : 32;
        int rpb = (Mrows + nblk - 1) / nblk;
        bn_stats<<<nblk, 256, 0, stream>>>(h, st, Mrows, rpb);
        bn_fin<<<1, 256, 0, stream>>>(st, g, be, 1.f / (float)Mrows);
    };

    // --- setup ---
    hipMemsetAsync(flags, 0, 12 * 240 * 4, stream);
    decode_k<<<1, 256, 0, stream>>>(rel_rec, rel_send, sidx, ridx, nodeEdges);
    for (int i = 0; i < 7; ++i)
        cvt16<<<(wsz[i] + 255) / 256, 256, 0, stream>>>(wsrc[i], w16[i], wsz[i]);
    cvtperm<<<3072, 256, 0, stream>>>(lstm_wih, wihp);
    wprep2<<<384, 256, 0, stream>>>(lstm_whh, W2);

    // --- MLP1 ---
    mlp1_g1<<<8192, 256, 0, stream>>>(inputs, mw1[0], mb1[0], h1);
    gemmg<M_ID, true><<<dim3(64, 2), 256, 0, stream>>>(
        h1, nullptr, nullptr, nullptr, sidx, ridx, w16[0], mb2[0], h1b, 8192, 256, 0);
    bn(h1b, 8192, st1, mg[0], mbe[0]);

    // --- MLP2 (node2edge gather + bn1 fused) ---
    gemmg<M_N2E, true><<<dim3(960, 2), 256, 0, stream>>>(
        h1b, nullptr, st1, nullptr, sidx, ridx, w16[1], mb1[1], P, 122880, 256, 0);
    gemmg<M_ID, true><<<dim3(960, 2), 256, 0, stream>>>(
        P, nullptr, nullptr, nullptr, sidx, ridx, w16[2], mb2[1], Q, 122880, 256, 0);
    bn(Q, 122880, st2, mg[1], mbe[1]);

    // --- edge2node (bn2 fused) + MLP3 ---
    e2n_k<<<1024, 256, 0, stream>>>(Q, st2, nodeEdges, xn);
    gemmg<M_ID, true><<<dim3(64, 2), 256, 0, stream>>>(
        xn, nullptr, nullptr, nullptr, sidx, ridx, w16[3], mb1[2], x3h, 8192, 256, 0);
    gemmg<M_ID, true><<<dim3(64, 2), 256, 0, stream>>>(
        x3h, nullptr, nullptr, nullptr, sidx, ridx, w16[4], mb2[2], x3raw, 8192, 256, 0);
    bn(x3raw, 8192, st3, mg[2], mbe[2]);

    // --- MLP4 (gather bn3(x3) + skip bn2(Q)) ---
    gemmg<M_M4, true><<<dim3(960, 2), 256, 0, stream>>>(
        x3raw, Q, st3, st2, sidx, ridx, w16[5], mb1[3], P, 122880, 256, 0);
    gemmg<M_ID, true><<<dim3(960, 2), 256, 0, stream>>>(
        P, nullptr, nullptr, nullptr, sidx, ridx, w16[6], mb2[3], Q, 122880, 256, 0);
    bn(Q, 122880, st4, mg[3], mbe[3]);

    // --- 3-layer LSTM: per layer, per 16-step chunk: xw GEMM + recurrent ---
    for (int l = 0; l < 3; ++l) {
        const _Float16* wih_l = wihp + (size_t)l * 262144;
        const _Float16* W2l   = W2 + (size_t)l * 262144;
        const float* bih_l = lstm_bih + l * 1024;
        const float* bhh_l = lstm_bhh + l * 1024;
        _Float16* hout_l = (l < 2) ? P : nullptr;
        _Float16* hfin_l = (l == 2) ? hfinal : nullptr;
        for (int c = 0; c < 4; ++c) {
            int tc = c * 16;
            if (l == 0)
                gemmg<M_L0C, false><<<dim3(240, 8), 256, 0, stream>>>(
                    Q, nullptr, st4, nullptr, sidx, ridx, wih_l, nullptr,
                    XW, 30720, 1024, tc);
            else
                gemmg<M_IDC, false><<<dim3(240, 8), 256, 0, stream>>>(
                    P, nullptr, nullptr, nullptr, sidx, ridx, wih_l, nullptr,
                    XW, 30720, 1024, tc);
            rec_k<<<256, 256, 0, stream>>>(
                XW, W2l, bih_l, bhh_l, hout_l, hfin_l,
                hexbuf, flags + (l * 4 + c) * 240, tc, hstate, cstate);
        }
    }

    // --- final FC ---
    fco_k<<<1920, 64, 0, stream>>>(hfinal, fco_w, fco_b, out);
}

// Round 13
// 3095.724 us; speedup vs baseline: 1.1220x; 1.1220x over previous
//
#include <hip/hip_runtime.h>

// GRNN (NRI) encoder, MI355X gfx950.
// B=8, N=16, T=64, D=4, H=256, E=240, BT=512, BR=1920.
// MLPs/xw: fp16 MFMA gather-GEMMs with global_load_lds staging (W always;
// A too when no BN fusion), BN fused into consumer staging where needed.
// LSTM: x@Wih^T per 16-step chunk (gate-interleaved); recurrent part =
// 240 co-resident blocks (60 rgrps x 4 colq, same-XCD siblings), Whh slice
// (128 KB) persistent in LDS, h-quadrant exchange via agent-scope parity
// mailboxes (round-9 structure, measured best).

typedef __attribute__((ext_vector_type(4))) float f32x4;
typedef __attribute__((ext_vector_type(8))) _Float16 f16x8;
typedef unsigned long long u64;

#define DEVFN static __device__ __forceinline__

DEVFN float elu_f(float x)  { return x > 0.f ? x : __expf(x) - 1.f; }
DEVFN float sig_f(float x)  { return 1.f / (1.f + __expf(-x)); }
DEVFN float tanh_f(float x) { return 1.f - 2.f / (1.f + __expf(2.f * x)); }

// async global->LDS, 16B per lane (dest = wave-uniform base + lane*16)
#define GLD(gp, lp) __builtin_amdgcn_global_load_lds( \
    (const __attribute__((address_space(1))) unsigned int*)(const void*)(gp), \
    (__attribute__((address_space(3))) unsigned int*)(void*)(lp), 16, 0, 0)

#define M_ID  0
#define M_N2E 1
#define M_M4  2
#define M_L0C 3   // xw0 chunk: q=(r*16+tt): A0[(b*64+tc+tt)*240+e], BN st0
#define M_IDC 4   // xw1/2 chunk: A0[(q>>4)*64 + tc + (q&15)]

// ---------------------------------------------------------------------------
// Gather-GEMM: out[M,O] = epi(gatherA[M,K] @ W[O,K]^T + bias).
// W tile staged via global_load_lds (linear [128][32]); A tile likewise when
// no BN fusion (M_ID / M_IDC), else register-staged into padded As.
// ---------------------------------------------------------------------------
template<int MODE, bool DOELU>
__global__ __launch_bounds__(256) void gemmg(
    const _Float16* __restrict__ A0, const _Float16* __restrict__ A1,
    const float* __restrict__ st0, const float* __restrict__ st1,
    const int* __restrict__ sidx, const int* __restrict__ ridx,
    const _Float16* __restrict__ W, const float* __restrict__ bias,
    _Float16* __restrict__ out, int M, int O, int tc)
{
    constexpr int NSEG = (MODE == M_M4) ? 3 : ((MODE == M_N2E) ? 2 : 1);
    constexpr bool HAS_ST = (MODE == M_N2E) || (MODE == M_M4) || (MODE == M_L0C);
    constexpr bool AGLD = (MODE == M_ID) || (MODE == M_IDC);
    const int K = NSEG * 256;

    __shared__ char AsBuf[10240];          // padded [128][40] OR linear [128][32]
    __shared__ _Float16 WsL[4096];         // linear [128][32]
    _Float16 (*AsP)[40] = (_Float16 (*)[40])AsBuf;
    _Float16* AsLf = (_Float16*)AsBuf;

    const int tid  = threadIdx.x;
    const int lane = tid & 63;
    const int wv   = tid >> 6;
    const int wr   = wv >> 1, wc = wv & 1;
    const int lr   = lane & 15, kg = lane >> 4;
    const int m0   = blockIdx.x * 128;
    const int o0   = blockIdx.y * 128;
    const int srow = tid >> 1;
    const int scol = (tid & 1) * 16;

    // reg-staged A sources (BN-fused modes)
    const _Float16* ab[3] = {nullptr, nullptr, nullptr};
    const float*   stp[3] = {nullptr, nullptr, nullptr};
    if constexpr (!AGLD) {
        int r = m0 + srow;
        if constexpr (MODE == M_N2E) {
            int bt = r / 240, e = r - bt * 240;
            ab[0] = A0 + (size_t)(bt * 16 + sidx[e]) * 256;
            ab[1] = A0 + (size_t)(bt * 16 + ridx[e]) * 256;
            stp[0] = st0; stp[1] = st0;
        } else if constexpr (MODE == M_M4) {
            int bt = r / 240, e = r - bt * 240;
            ab[0] = A0 + (size_t)(bt * 16 + sidx[e]) * 256;
            ab[1] = A0 + (size_t)(bt * 16 + ridx[e]) * 256;
            ab[2] = A1 + (size_t)r * 256;
            stp[0] = st0; stp[1] = st0; stp[2] = st1;
        } else if constexpr (MODE == M_L0C) {
            int rr = r >> 4, tt = r & 15;
            int b = rr / 240, e = rr - b * 240;
            ab[0] = A0 + (size_t)((b * 64 + tc + tt) * 240 + e) * 256;
            stp[0] = st0;
        }
    }

    // gld sources: per-lane rows, wave-uniform LDS dests
    const int rA0 = 2 * wv * 16 + (lane >> 2);
    const int rA1 = rA0 + 16;
    const int cL  = (lane & 3) * 8;
    const _Float16* aSrc0 = nullptr;
    const _Float16* aSrc1 = nullptr;
    if constexpr (MODE == M_ID) {
        aSrc0 = A0 + (size_t)(m0 + rA0) * 256 + cL;
        aSrc1 = A0 + (size_t)(m0 + rA1) * 256 + cL;
    } else if constexpr (MODE == M_IDC) {
        int r0_ = m0 + rA0, r1_ = m0 + rA1;
        aSrc0 = A0 + (size_t)((r0_ >> 4) * 64 + tc + (r0_ & 15)) * 256 + cL;
        aSrc1 = A0 + (size_t)((r1_ >> 4) * 64 + tc + (r1_ & 15)) * 256 + cL;
    }
    const _Float16* wSrc0 = W + (size_t)(o0 + rA0) * K + cL;
    const _Float16* wSrc1 = W + (size_t)(o0 + rA1) * K + cL;
    _Float16* aDst0 = AsLf + (2 * wv + 0) * 512;
    _Float16* aDst1 = AsLf + (2 * wv + 1) * 512;
    _Float16* wDst0 = WsL  + (2 * wv + 0) * 512;
    _Float16* wDst1 = WsL  + (2 * wv + 1) * 512;

    f32x4 acc[4][4];
#pragma unroll
    for (int i = 0; i < 4; ++i)
#pragma unroll
        for (int j = 0; j < 4; ++j) acc[i][j] = (f32x4)0.f;

#pragma unroll
    for (int seg = 0; seg < NSEG; ++seg) {
        const _Float16* asrc = ab[seg];
        const float*    st   = stp[seg];
#pragma unroll 1
        for (int kk = 0; kk < 256; kk += 32) {
            const int ko = seg * 256 + kk;
            if constexpr (AGLD) {
                GLD(aSrc0 + kk, aDst0);
                GLD(aSrc1 + kk, aDst1);
            } else {
                f16x8 v0 = *(const f16x8*)(asrc + kk + scol);
                f16x8 v1 = *(const f16x8*)(asrc + kk + scol + 8);
                if constexpr (HAS_ST) {
#pragma unroll
                    for (int j = 0; j < 8; ++j) {
                        int c0 = kk + scol + j, c1 = c0 + 8;
                        v0[j] = (_Float16)((float)v0[j] * st[512 + c0] + st[768 + c0]);
                        v1[j] = (_Float16)((float)v1[j] * st[512 + c1] + st[768 + c1]);
                    }
                }
                *(f16x8*)&AsP[srow][scol]     = v0;
                *(f16x8*)&AsP[srow][scol + 8] = v1;
            }
            GLD(wSrc0 + ko, wDst0);
            GLD(wSrc1 + ko, wDst1);
            __syncthreads();   // drains vmcnt (gld) + lgkm

            f16x8 af[4], bf[4];
#pragma unroll
            for (int rf = 0; rf < 4; ++rf) {
                if constexpr (AGLD)
                    af[rf] = *(const f16x8*)&AsLf[(wr * 64 + rf * 16 + lr) * 32 + kg * 8];
                else
                    af[rf] = *(const f16x8*)&AsP[wr * 64 + rf * 16 + lr][kg * 8];
            }
#pragma unroll
            for (int cf = 0; cf < 4; ++cf)
                bf[cf] = *(const f16x8*)&WsL[(wc * 64 + cf * 16 + lr) * 32 + kg * 8];
#pragma unroll
            for (int rf = 0; rf < 4; ++rf)
#pragma unroll
                for (int cf = 0; cf < 4; ++cf)
                    acc[rf][cf] = __builtin_amdgcn_mfma_f32_16x16x32_f16(
                        af[rf], bf[cf], acc[rf][cf], 0, 0, 0);
            __syncthreads();   // reads done before next stage overwrites
        }
    }

#pragma unroll
    for (int rf = 0; rf < 4; ++rf) {
#pragma unroll
        for (int cf = 0; cf < 4; ++cf) {
            int c = o0 + wc * 64 + cf * 16 + lr;
            float bv = bias ? bias[c] : 0.f;
#pragma unroll
            for (int rg = 0; rg < 4; ++rg) {
                int r = m0 + wr * 64 + rf * 16 + kg * 4 + rg;
                float v = acc[rf][cf][rg] + bv;
                if (DOELU) v = elu_f(v);
                out[(size_t)r * O + c] = (_Float16)v;
            }
        }
    }
}

// ---------------------------------------------------------------------------
__global__ void mlp1_g1(const float* __restrict__ inp, const float* __restrict__ w1,
                        const float* __restrict__ b1, _Float16* __restrict__ out)
{
    int idx = blockIdx.x * 256 + threadIdx.x;
    int o = idx & 255, row = idx >> 8;
    int bt = row >> 4, n = row & 15, b = bt >> 6, t = bt & 63;
    const float* xp = inp + (((b * 16 + n) * 64 + t) << 2);
    const float* wp = w1 + (o << 2);
    float v = b1[o] + xp[0] * wp[0] + xp[1] * wp[1] + xp[2] * wp[2] + xp[3] * wp[3];
    out[idx] = (_Float16)elu_f(v);
}

__global__ void decode_k(const float* __restrict__ rel_rec, const float* __restrict__ rel_send,
                         int* __restrict__ sidx, int* __restrict__ ridx,
                         int* __restrict__ nodeEdges)
{
    int tid = threadIdx.x;
    if (tid < 240) {
        float as = 0.f, ar = 0.f;
        for (int n = 0; n < 16; ++n) {
            as += rel_send[tid * 16 + n] * (float)n;
            ar += rel_rec[tid * 16 + n] * (float)n;
        }
        sidx[tid] = (int)(as + 0.5f);
        ridx[tid] = (int)(ar + 0.5f);
    }
    __syncthreads();
    if (tid < 16) {
        int k = 0;
        for (int e = 0; e < 240; ++e)
            if (ridx[e] == tid) nodeEdges[tid * 15 + (k++)] = e;
    }
}

__global__ void cvt16(const float* __restrict__ src, _Float16* __restrict__ dst, int n)
{
    int i = blockIdx.x * 256 + threadIdx.x;
    if (i < n) dst[i] = (_Float16)src[i];
}

// Wih rows permuted so GEMM output col c' = [hcol=c'>>2][gate=c'&3]
__global__ void cvtperm(const float* __restrict__ src, _Float16* __restrict__ dst)
{
    int idx = blockIdx.x * 256 + threadIdx.x;   // 786432 total
    int k = idx & 255;
    int cp = (idx >> 8) & 1023;
    int l = idx >> 18;
    dst[idx] = (_Float16)src[((size_t)l * 1024 + (cp & 3) * 256 + (cp >> 2)) * 256 + k];
}

// ---------------------------------------------------------------------------
// Whh fragment pack: W2[l][cq][w4][g][kc][lane][8] f16
// ---------------------------------------------------------------------------
__global__ void wprep2(const float* __restrict__ whh, _Float16* __restrict__ W2)
{
    int idx = blockIdx.x * 256 + threadIdx.x;   // 98304 total
    int lane = idx & 63; int u = idx >> 6;
    int kc = u & 7; u >>= 3;
    int g  = u & 3; u >>= 2;
    int w  = u & 3; u >>= 2;
    int cq = u & 3; u >>= 2;
    int l  = u;
    int gatecol = g * 256 + cq * 64 + w * 16 + (lane & 15);
    int k = kc * 32 + (lane >> 4) * 8;
    const float* src = whh + (size_t)l * 262144 + (size_t)gatecol * 256 + k;
    f16x8 v;
#pragma unroll
    for (int j = 0; j < 8; ++j) v[j] = (_Float16)src[j];
    *(f16x8*)&W2[(size_t)idx * 8] = v;
}

// ---------------------------------------------------------------------------
__global__ void bn_stats(const _Float16* __restrict__ h, float* __restrict__ stats,
                         int Mrows, int rowsPerBlk)
{
    int col = threadIdx.x;
    int r0 = blockIdx.x * rowsPerBlk;
    int r1 = r0 + rowsPerBlk; if (r1 > Mrows) r1 = Mrows;
    float s = 0.f, q = 0.f;
    for (int r = r0; r < r1; ++r) {
        float v = (float)h[(size_t)r * 256 + col];
        s += v; q += v * v;
    }
    atomicAdd(&stats[col], s);
    atomicAdd(&stats[256 + col], q);
}

__global__ void bn_fin(float* __restrict__ stats, const float* __restrict__ g,
                       const float* __restrict__ be, float invM)
{
    int c = threadIdx.x;
    float m  = stats[c] * invM;
    float vr = stats[256 + c] * invM - m * m;
    float sc = rsqrtf(vr + 1e-5f) * g[c];
    stats[512 + c] = sc;
    stats[768 + c] = be[c] - m * sc;
}

__global__ void e2n_k(const _Float16* __restrict__ x2, const float* __restrict__ st,
                      const int* __restrict__ nodeEdges, _Float16* __restrict__ out)
{
    int idx = blockIdx.x * 256 + threadIdx.x;
    int c = (idx & 31) * 8;
    int n = (idx >> 5) & 15;
    int bt = idx >> 9;
    float s[8] = {0, 0, 0, 0, 0, 0, 0, 0};
    for (int k = 0; k < 15; ++k) {
        int e = nodeEdges[n * 15 + k];
        f16x8 v = *(const f16x8*)&x2[(size_t)(bt * 240 + e) * 256 + c];
#pragma unroll
        for (int j = 0; j < 8; ++j) s[j] += (float)v[j];
    }
    f16x8 r;
#pragma unroll
    for (int j = 0; j < 8; ++j)
        r[j] = (_Float16)((st[512 + c + j] * s[j] + 15.f * st[768 + c + j]) * 0.0625f);
    *(f16x8*)&out[(size_t)(bt * 16 + n) * 256 + c] = r;
}

// ---------------------------------------------------------------------------
// Recurrent chunk kernel (round-9 structure, measured best: 163 us).
// Grid 256 (16 idle): colq = blockIdx>>6, rgrp = blockIdx&63 (same-XCD sibs).
// 256 threads (4 waves); wave w owns h-cols colq*64 + w*16 + lr, 2 row tiles.
// ---------------------------------------------------------------------------
#define STEP(TT, XPU, XPN) do {                                                \
    const int t_ = tc + (TT);                                                  \
    const int ttn_ = ((TT) < 15) ? (TT) + 1 : 15;                              \
    _Pragma("unroll")                                                          \
    for (int rt = 0; rt < 2; ++rt)                                             \
        _Pragma("unroll")                                                      \
        for (int rg = 0; rg < 4; ++rg) {                                       \
            int row = rt * 16 + kg * 4 + rg;                                   \
            XPN[rt * 4 + rg] = *(const u64*)(xwb                               \
                + ((size_t)(r0 + row) * 16 + ttn_) * 1024);                    \
        }                                                                      \
    f32x4 acc[4][2];                                                           \
    _Pragma("unroll")                                                          \
    for (int g = 0; g < 4; ++g)                                                \
        _Pragma("unroll")                                                      \
        for (int rt = 0; rt < 2; ++rt) acc[g][rt] = (f32x4)0.f;                \
    _Pragma("unroll")                                                          \
    for (int kc = 0; kc < 8; ++kc) {                                           \
        const int kb = kc * 64 + kg * 16;                                      \
        const int o0_ = (lr * 512 + kb) ^ ((lr & 7) << 4);                     \
        const int o1_ = ((16 + lr) * 512 + kb) ^ (((16 + lr) & 7) << 4);       \
        f16x8 a0 = *(const f16x8*)(hfulb + o0_);                               \
        f16x8 a1 = *(const f16x8*)(hfulb + o1_);                               \
        _Pragma("unroll")                                                      \
        for (int g = 0; g < 4; ++g) {                                          \
            f16x8 bf = *(const f16x8*)&Wlds[(((w * 4 + g) * 8 + kc) * 64 + lane) * 8]; \
            acc[g][0] = __builtin_amdgcn_mfma_f32_16x16x32_f16(a0, bf, acc[g][0], 0, 0, 0); \
            acc[g][1] = __builtin_amdgcn_mfma_f32_16x16x32_f16(a1, bf, acc[g][1], 0, 0, 0); \
        }                                                                      \
    }                                                                          \
    __syncthreads();                                                           \
    _Float16 hv0[4], hv1[4];                                                   \
    _Pragma("unroll")                                                          \
    for (int rt = 0; rt < 2; ++rt)                                             \
        _Pragma("unroll")                                                      \
        for (int rg = 0; rg < 4; ++rg) {                                       \
            int row = rt * 16 + kg * 4 + rg;                                   \
            union { u64 u; _Float16 h[4]; } xu; xu.u = XPU[rt * 4 + rg];       \
            float gi = acc[0][rt][rg] + (float)xu.h[0] + bs[0];                \
            float gf = acc[1][rt][rg] + (float)xu.h[1] + bs[1];                \
            float gg = acc[2][rt][rg] + (float)xu.h[2] + bs[2];                \
            float go = acc[3][rt][rg] + (float)xu.h[3] + bs[3];                \
            float c  = sig_f(gf) * cst[rt][rg] + sig_f(gi) * tanh_f(gg);       \
            cst[rt][rg] = c;                                                   \
            float h = sig_f(go) * tanh_f(c);                                   \
            _Float16 h16 = (_Float16)h;                                        \
            if (rt == 0) hv0[rg] = h16; else hv1[rg] = h16;                    \
            int off = (row * 512 + col * 2) ^ ((row & 7) << 4);                \
            *(_Float16*)(hfulb + off) = h16;                                   \
        }                                                                      \
    {                                                                          \
        const int lc = w * 16 + lr;                                            \
        union { _Float16 h[4]; u64 u; } pk;                                    \
        pk.h[0] = hv0[0]; pk.h[1] = hv0[1]; pk.h[2] = hv0[2]; pk.h[3] = hv0[3];\
        u64 p0 = pk.u;                                                         \
        pk.h[0] = hv1[0]; pk.h[1] = hv1[1]; pk.h[2] = hv1[2]; pk.h[3] = hv1[3];\
        u64 p1 = pk.u;                                                         \
        u64* hb = hex + ((size_t)fid * 2 + (t_ & 1)) * 512;                    \
        __hip_atomic_store(&hb[(lc * 2 + 0) * 4 + kg], p0,                     \
                           __ATOMIC_RELAXED, __HIP_MEMORY_SCOPE_AGENT);        \
        __hip_atomic_store(&hb[(lc * 2 + 1) * 4 + kg], p1,                     \
                           __ATOMIC_RELAXED, __HIP_MEMORY_SCOPE_AGENT);        \
    }                                                                          \
    __syncthreads();                                                           \
    if (tid == 0)                                                              \
        __hip_atomic_store(&flags[fid], t_ + 1,                                \
                           __ATOMIC_RELEASE, __HIP_MEMORY_SCOPE_AGENT);        \
    if (tid < 3) {                                                             \
        int s = tid + (tid >= colq ? 1 : 0);                                   \
        while (__hip_atomic_load(&flags[rgrp * 4 + s],                         \
                 __ATOMIC_ACQUIRE, __HIP_MEMORY_SCOPE_AGENT) < t_ + 1) {}      \
    }                                                                          \
    __syncthreads();                                                           \
    _Pragma("unroll 1")                                                        \
    for (int i = tid; i < 1536; i += 256) {                                    \
        int sbi = i >> 9;                                                      \
        int sq  = sbi + (sbi >= colq ? 1 : 0);                                 \
        int idx = i & 511;                                                     \
        u64 v = __hip_atomic_load(                                             \
            &hex[(((size_t)rgrp * 4 + sq) * 2 + (t_ & 1)) * 512 + idx],        \
            __ATOMIC_RELAXED, __HIP_MEMORY_SCOPE_AGENT);                       \
        int lc = idx >> 3, rt = (idx >> 2) & 1, k4 = idx & 3;                  \
        int cg = sq * 64 + lc;                                                 \
        union { u64 u; _Float16 h[4]; } un; un.u = v;                          \
        _Pragma("unroll")                                                      \
        for (int rg = 0; rg < 4; ++rg) {                                       \
            int row = rt * 16 + k4 * 4 + rg;                                   \
            int off = (row * 512 + cg * 2) ^ ((row & 7) << 4);                 \
            *(_Float16*)(hfulb + off) = un.h[rg];                              \
        }                                                                      \
    }                                                                          \
    __syncthreads();                                                           \
    {                                                                          \
        int row = tid >> 3, cg = colq * 64 + (tid & 7) * 8;                    \
        int off = (row * 512 + cg * 2) ^ ((row & 7) << 4);                     \
        if (hout) {                                                            \
            f16x8 v = *(const f16x8*)(hfulb + off);                            \
            *(f16x8*)&hout[((size_t)(r0 + row) * 64 + t_) * 256 + cg] = v;     \
        }                                                                      \
        if (hfinal && t_ == 63) {                                              \
            f16x8 v = *(const f16x8*)(hfulb + off);                            \
            *(f16x8*)&hfinal[(size_t)(r0 + row) * 256 + cg] = v;               \
        }                                                                      \
        if ((TT) == 15) {                                                      \
            f16x8 v = *(const f16x8*)(hfulb + off);                            \
            *(f16x8*)&hstate[(size_t)(r0 + row) * 256 + cg] = v;               \
            _Pragma("unroll")                                                  \
            for (int rt = 0; rt < 2; ++rt)                                     \
                _Pragma("unroll")                                              \
                for (int rg = 0; rg < 4; ++rg)                                 \
                    cstate[(size_t)(r0 + rt * 16 + kg * 4 + rg) * 256 + col] = cst[rt][rg]; \
        }                                                                      \
    }                                                                          \
} while (0)

__global__ __launch_bounds__(256) void rec_k(
    const _Float16* __restrict__ xw,     // [30720,1024] gate-interleaved
    const _Float16* __restrict__ W2l,    // [cq][w4][g][kc][64][8]
    const float* __restrict__ bih, const float* __restrict__ bhh,   // [1024]
    _Float16* __restrict__ hout,         // [122880,256] or null
    _Float16* __restrict__ hfinal,       // [1920,256] or null
    u64* __restrict__ hex,               // [240][2][512]
    int* __restrict__ flags,             // [240] zeroed per chunk
    int tc,
    _Float16* __restrict__ hstate,       // [1920,256]
    float* __restrict__ cstate)          // [1920,256]
{
    __shared__ _Float16 Wlds[65536];     // 128 KB
    __shared__ char hfulb[16384];        // [32][256] f16, XOR-swizzled

    const int colq = blockIdx.x >> 6;
    const int rgrp = blockIdx.x & 63;
    if (rgrp >= 60) return;

    const int tid  = threadIdx.x;
    const int lane = tid & 63;
    const int w    = tid >> 6;
    const int lr   = lane & 15, kg = lane >> 4;
    const int fid  = rgrp * 4 + colq;
    const int r0   = rgrp * 32;
    const int col  = colq * 64 + w * 16 + lr;

    {
        const f16x8* src = (const f16x8*)(W2l + (size_t)colq * 65536);
        f16x8* dst = (f16x8*)Wlds;
        for (int i = tid; i < 8192; i += 256) dst[i] = src[i];
    }

    float cst[2][4];
    if (tc == 0) {
        for (int i = tid; i < 2048; i += 256) ((u64*)hfulb)[i] = 0ULL;
#pragma unroll
        for (int rt = 0; rt < 2; ++rt)
#pragma unroll
            for (int rg = 0; rg < 4; ++rg) cst[rt][rg] = 0.f;
    } else {
        for (int i = tid; i < 1024; i += 256) {
            int row = i >> 5, c8 = (i & 31) * 8;
            f16x8 v = *(const f16x8*)&hstate[(size_t)(r0 + row) * 256 + c8];
            int off = (row * 512 + c8 * 2) ^ ((row & 7) << 4);
            *(f16x8*)(hfulb + off) = v;
        }
#pragma unroll
        for (int rt = 0; rt < 2; ++rt)
#pragma unroll
            for (int rg = 0; rg < 4; ++rg)
                cst[rt][rg] = cstate[(size_t)(r0 + rt * 16 + kg * 4 + rg) * 256 + col];
    }

    float bs[4];
#pragma unroll
    for (int g = 0; g < 4; ++g) bs[g] = bih[g * 256 + col] + bhh[g * 256 + col];

    const _Float16* xwb = xw + (size_t)col * 4;

    u64 xpA[8], xpB[8];
#pragma unroll
    for (int rt = 0; rt < 2; ++rt)
#pragma unroll
        for (int rg = 0; rg < 4; ++rg) {
            int row = rt * 16 + kg * 4 + rg;
            xpA[rt * 4 + rg] = *(const u64*)(xwb + (size_t)(r0 + row) * 16 * 1024);
        }
    __syncthreads();

#pragma unroll 1
    for (int it = 0; it < 8; ++it) {
        STEP(it * 2,     xpA, xpB);
        STEP(it * 2 + 1, xpB, xpA);
    }
}

// Final FC: out[r, 0:2] = hfinal[r] @ fco_w^T + fco_b
__global__ void fco_k(const _Float16* __restrict__ hout, const float* __restrict__ w,
                      const float* __restrict__ b, float* __restrict__ out)
{
    int row = blockIdx.x;
    int lane = threadIdx.x;   // 64
    const _Float16* hp = hout + (size_t)row * 256;
    float s0 = 0.f, s1 = 0.f;
    for (int k = lane; k < 256; k += 64) {
        float v = (float)hp[k];
        s0 += v * w[k];
        s1 += v * w[256 + k];
    }
#pragma unroll
    for (int off = 32; off; off >>= 1) {
        s0 += __shfl_down(s0, off, 64);
        s1 += __shfl_down(s1, off, 64);
    }
    if (lane == 0) {
        out[row * 2 + 0] = s0 + b[0];
        out[row * 2 + 1] = s1 + b[1];
    }
}

// ---------------------------------------------------------------------------
extern "C" void kernel_launch(void* const* d_in, const int* in_sizes, int n_in,
                              void* d_out, int out_size, void* d_ws, size_t ws_size,
                              hipStream_t stream)
{
    const float* inputs   = (const float*)d_in[0];
    const float* rel_rec  = (const float*)d_in[1];
    const float* rel_send = (const float*)d_in[2];
    const float *mw1[4], *mb1[4], *mw2[4], *mb2[4], *mg[4], *mbe[4];
    for (int i = 0; i < 4; ++i) {
        mw1[i] = (const float*)d_in[3 + 6 * i + 0];
        mb1[i] = (const float*)d_in[3 + 6 * i + 1];
        mw2[i] = (const float*)d_in[3 + 6 * i + 2];
        mb2[i] = (const float*)d_in[3 + 6 * i + 3];
        mg [i] = (const float*)d_in[3 + 6 * i + 4];
        mbe[i] = (const float*)d_in[3 + 6 * i + 5];
    }
    const float* lstm_wih = (const float*)d_in[27];
    const float* lstm_whh = (const float*)d_in[28];
    const float* lstm_bih = (const float*)d_in[29];
    const float* lstm_bhh = (const float*)d_in[30];
    const float* fco_w    = (const float*)d_in[31];
    const float* fco_b    = (const float*)d_in[32];
    float* out = (float*)d_out;
    (void)in_sizes; (void)n_in; (void)out_size; (void)ws_size;

    char* ws = (char*)d_ws;
    size_t off = 0;
    auto alloc = [&](size_t bytes) -> void* {
        void* p = ws + off;
        off = (off + bytes + 255) & ~(size_t)255;
        return p;
    };

    float* stats    = (float*)alloc(4 * 1024 * 4);
    int*   sidx     = (int*)alloc(240 * 4);
    int*   ridx     = (int*)alloc(240 * 4);
    int*   nodeEdges= (int*)alloc(240 * 4);
    int*   flags    = (int*)alloc(12 * 240 * 4);
    u64*   hexbuf   = (u64*)alloc((size_t)240 * 2 * 512 * 8);

    const int wsz[7] = {65536, 131072, 65536, 65536, 65536, 196608, 65536};
    const float* wsrc[7] = {mw2[0], mw1[1], mw2[1], mw1[2], mw2[2], mw1[3], mw2[3]};
    _Float16* w16[7];
    for (int i = 0; i < 7; ++i) w16[i] = (_Float16*)alloc((size_t)wsz[i] * 2);
    _Float16* wihp = (_Float16*)alloc((size_t)786432 * 2);    // gate-permuted Wih
    _Float16* W2   = (_Float16*)alloc((size_t)786432 * 2);    // packed Whh frags

    const size_t SM = (size_t)8192 * 256;
    _Float16* h1    = (_Float16*)alloc(SM * 2);
    _Float16* h1b   = (_Float16*)alloc(SM * 2);
    _Float16* xn    = (_Float16*)alloc(SM * 2);
    _Float16* x3h   = (_Float16*)alloc(SM * 2);
    _Float16* x3raw = (_Float16*)alloc(SM * 2);
    _Float16* hfinal= (_Float16*)alloc((size_t)1920 * 256 * 2);
    _Float16* hstate= (_Float16*)alloc((size_t)1920 * 256 * 2);
    float*    cstate= (float*)alloc((size_t)1920 * 256 * 4);

    const size_t BIG = (size_t)122880 * 256;
    _Float16* P  = (_Float16*)alloc(BIG * 2);                 // also hout
    _Float16* Q  = (_Float16*)alloc(BIG * 2);
    _Float16* XW = (_Float16*)alloc((size_t)30720 * 1024 * 2);

    float* st1 = stats, *st2 = stats + 1024, *st3 = stats + 2048, *st4 = stats + 3072;

    auto bn = [&](const _Float16* h, int Mrows, float* st, const float* g, const float* be) {
        hipMemsetAsync(st, 0, 512 * sizeof(float), stream);
        int nblk = (Mrows > 20000) ? 240 : 32;
        int rpb = (Mrows + nblk - 1) / nblk;
        bn_stats<<<nblk, 256, 0, stream>>>(h, st, Mrows, rpb);
        bn_fin<<<1, 256, 0, stream>>>(st, g, be, 1.f / (float)Mrows);
    };

    // --- setup ---
    hipMemsetAsync(flags, 0, 12 * 240 * 4, stream);
    decode_k<<<1, 256, 0, stream>>>(rel_rec, rel_send, sidx, ridx, nodeEdges);
    for (int i = 0; i < 7; ++i)
        cvt16<<<(wsz[i] + 255) / 256, 256, 0, stream>>>(wsrc[i], w16[i], wsz[i]);
    cvtperm<<<3072, 256, 0, stream>>>(lstm_wih, wihp);
    wprep2<<<384, 256, 0, stream>>>(lstm_whh, W2);

    // --- MLP1 ---
    mlp1_g1<<<8192, 256, 0, stream>>>(inputs, mw1[0], mb1[0], h1);
    gemmg<M_ID, true><<<dim3(64, 2), 256, 0, stream>>>(
        h1, nullptr, nullptr, nullptr, sidx, ridx, w16[0], mb2[0], h1b, 8192, 256, 0);
    bn(h1b, 8192, st1, mg[0], mbe[0]);

    // --- MLP2 (node2edge gather + bn1 fused) ---
    gemmg<M_N2E, true><<<dim3(960, 2), 256, 0, stream>>>(
        h1b, nullptr, st1, nullptr, sidx, ridx, w16[1], mb1[1], P, 122880, 256, 0);
    gemmg<M_ID, true><<<dim3(960, 2), 256, 0, stream>>>(
        P, nullptr, nullptr, nullptr, sidx, ridx, w16[2], mb2[1], Q, 122880, 256, 0);
    bn(Q, 122880, st2, mg[1], mbe[1]);

    // --- edge2node (bn2 fused) + MLP3 ---
    e2n_k<<<1024, 256, 0, stream>>>(Q, st2, nodeEdges, xn);
    gemmg<M_ID, true><<<dim3(64, 2), 256, 0, stream>>>(
        xn, nullptr, nullptr, nullptr, sidx, ridx, w16[3], mb1[2], x3h, 8192, 256, 0);
    gemmg<M_ID, true><<<dim3(64, 2), 256, 0, stream>>>(
        x3h, nullptr, nullptr, nullptr, sidx, ridx, w16[4], mb2[2], x3raw, 8192, 256, 0);
    bn(x3raw, 8192, st3, mg[2], mbe[2]);

    // --- MLP4 (gather bn3(x3) + skip bn2(Q)) ---
    gemmg<M_M4, true><<<dim3(960, 2), 256, 0, stream>>>(
        x3raw, Q, st3, st2, sidx, ridx, w16[5], mb1[3], P, 122880, 256, 0);
    gemmg<M_ID, true><<<dim3(960, 2), 256, 0, stream>>>(
        P, nullptr, nullptr, nullptr, sidx, ridx, w16[6], mb2[3], Q, 122880, 256, 0);
    bn(Q, 122880, st4, mg[3], mbe[3]);

    // --- 3-layer LSTM: per layer, per 16-step chunk: xw GEMM + recurrent ---
    for (int l = 0; l < 3; ++l) {
        const _Float16* wih_l = wihp + (size_t)l * 262144;
        const _Float16* W2l   = W2 + (size_t)l * 262144;
        const float* bih_l = lstm_bih + l * 1024;
        const float* bhh_l = lstm_bhh + l * 1024;
        _Float16* hout_l = (l < 2) ? P : nullptr;
        _Float16* hfin_l = (l == 2) ? hfinal : nullptr;
        for (int c = 0; c < 4; ++c) {
            int tc = c * 16;
            if (l == 0)
                gemmg<M_L0C, false><<<dim3(240, 8), 256, 0, stream>>>(
                    Q, nullptr, st4, nullptr, sidx, ridx, wih_l, nullptr,
                    XW, 30720, 1024, tc);
            else
                gemmg<M_IDC, false><<<dim3(240, 8), 256, 0, stream>>>(
                    P, nullptr, nullptr, nullptr, sidx, ridx, wih_l, nullptr,
                    XW, 30720, 1024, tc);
            rec_k<<<256, 256, 0, stream>>>(
                XW, W2l, bih_l, bhh_l, hout_l, hfin_l,
                hexbuf, flags + (l * 4 + c) * 240, tc, hstate, cstate);
        }
    }

    // --- final FC ---
    fco_k<<<1920, 64, 0, stream>>>(hfinal, fco_w, fco_b, out);
}